// Round 4
// baseline (211.603 us; speedup 1.0000x reference)
//
#include <hip/hip_runtime.h>
#include <hip/hip_bf16.h>

// EvoAttn: causal self-attention with Q=K=V = x.reshape(B,L,H,D).
// B=2 H=16 L=2048 D=128, fp32 in/out, bf16 MFMA compute.
// v4: 512-thread blocks (QB=128, 8 waves), 64KB LDS -> 16 waves/CU;
//     defer-max softmax, hw bf16 cvt, fma-folded scale, counted-vmcnt pipeline.

#define TL 2048
#define TE 2048
#define TD 128
#define KB 64
#define NTILES 32                          // TL / KB
#define TILE_B 16384                       // 64*128*2 bytes
#define KV_REGION (32 * NTILES * TILE_B)   // 16 MB per layout
#define WS_NEED (2u * (unsigned)KV_REGION) // 32 MB

typedef __attribute__((ext_vector_type(8))) short bf16x8;
typedef __attribute__((ext_vector_type(4))) float f32x4;
typedef __attribute__((ext_vector_type(8))) unsigned short u16x8;
typedef __attribute__((ext_vector_type(4))) unsigned short u16x4;

// (1/sqrt(128)) * log2(e)
#define SCALE_LOG2E 0.12751879f

__device__ __forceinline__ unsigned short f2bf(float f) {
  __hip_bfloat16 h = __float2bfloat16(f);
  return __builtin_bit_cast(unsigned short, h);
}

__device__ __forceinline__ f32x4 mfma16(bf16x8 a, bf16x8 b, f32x4 c) {
  return __builtin_amdgcn_mfma_f32_16x16x32_bf16(a, b, c, 0, 0, 0);
}

__device__ __forceinline__ void gl_lds16(const void* g, void* l) {
  __builtin_amdgcn_global_load_lds(
      (__attribute__((address_space(1))) void*)(g),
      (__attribute__((address_space(3))) void*)(l), 16, 0, 0);
}

// kv: [64 rows k][128 d] bf16, row stride 256B, byte ^= (k&7)<<4
// kvt:[128 rows d][64 k] bf16, row stride 128B, byte ^= (d&7)<<4
__device__ __forceinline__ void stage_tile(const float* __restrict__ src,
                                           unsigned short* kv, unsigned short* kvt,
                                           int t) {
  const int kr = (t >> 4) << 2;
  const int d0 = (t & 15) << 3;
  unsigned short c[4][8];
#pragma unroll
  for (int rr = 0; rr < 4; ++rr) {
    const float* p = src + (kr + rr) * TE + d0;
    const float4 a = *(const float4*)p;
    const float4 b = *(const float4*)(p + 4);
    c[rr][0] = f2bf(a.x); c[rr][1] = f2bf(a.y); c[rr][2] = f2bf(a.z); c[rr][3] = f2bf(a.w);
    c[rr][4] = f2bf(b.x); c[rr][5] = f2bf(b.y); c[rr][6] = f2bf(b.z); c[rr][7] = f2bf(b.w);
  }
#pragma unroll
  for (int rr = 0; rr < 4; ++rr) {
    const int r = kr + rr;
    u16x8 o = {c[rr][0], c[rr][1], c[rr][2], c[rr][3],
               c[rr][4], c[rr][5], c[rr][6], c[rr][7]};
    const int off = (r * 256 + d0 * 2) ^ ((r & 7) << 4);
    *(u16x8*)((char*)kv + off) = o;
  }
#pragma unroll
  for (int cc = 0; cc < 8; ++cc) {
    const int d = d0 + cc;
    u16x4 o = {c[0][cc], c[1][cc], c[2][cc], c[3][cc]};
    const int off = (d * 128 + kr * 2) ^ ((d & 7) << 4);
    *(u16x4*)((char*)kvt + off) = o;
  }
}

__device__ __forceinline__ bf16x8 ld256(const unsigned short* base, int row, int inrow) {
  const int off = (row * 256 + inrow) ^ ((row & 7) << 4);
  return *(const bf16x8*)((const char*)base + off);
}
__device__ __forceinline__ bf16x8 ld128(const unsigned short* base, int row, int inrow) {
  const int off = (row * 128 + inrow) ^ ((row & 7) << 4);
  return *(const bf16x8*)((const char*)base + off);
}

// ---------------- pre-pass: x (f32) -> pre-swizzled bf16 tile images in ws --
__global__ void __launch_bounds__(256)
prepack(const float* __restrict__ x, char* __restrict__ wsb) {
  __shared__ unsigned short kv[KB * TD];
  __shared__ unsigned short kvt[TD * KB];
  const int bid = blockIdx.x;            // bh*32 + kt
  const int kt = bid & 31;
  const int bh = bid >> 5;
  const int b = bh >> 4;
  const int h = bh & 15;
  const float* src = x + (size_t)b * TL * TE + h * TD + (size_t)kt * KB * TE;
  stage_tile(src, kv, kvt, threadIdx.x);
  __syncthreads();
  char* gkv = wsb + (size_t)bid * TILE_B;
  char* gkt = wsb + KV_REGION + (size_t)bid * TILE_B;
  const char* lv = (const char*)kv;
  const char* lt = (const char*)kvt;
  const int t = threadIdx.x;
#pragma unroll
  for (int i = 0; i < 4; ++i) {
    *(u16x8*)(gkv + t * 64 + i * 16) = *(const u16x8*)(lv + t * 64 + i * 16);
    *(u16x8*)(gkt + t * 64 + i * 16) = *(const u16x8*)(lt + t * 64 + i * 16);
  }
}

// ---------------- main attention kernel (8 waves, QB=128) -------------------
__global__ void __launch_bounds__(512, 4)
evo_attn2(const char* __restrict__ wsb, float* __restrict__ out) {
  // buf0 (16KB) | buf1 (16KB) | kvt (16KB) | pl (8 waves x 2KB) = 64 KB
  __shared__ char smem[4 * TILE_B];

  const int t = threadIdx.x;
  const int lane = t & 63;
  const int w = t >> 6;        // wave 0..7, owns q rows [q0+16w, q0+16w+16)
  const int g = lane >> 4;
  const int q15 = lane & 15;

  const int bh = blockIdx.x & 31;
  const int r_ = blockIdx.x >> 5;        // 0..15
  // interleave heavy/light so adjacent AND +256 pairings are balanced-ish
  const int QSEQ[16] = {15, 0, 13, 2, 11, 4, 9, 6, 8, 7, 10, 5, 12, 3, 14, 1};
  const int q2 = QSEQ[r_];
  const int b = bh >> 4;
  const int h = bh & 15;
  const int q0 = q2 * 128;
  const int nt = 2 * q2 + 2;             // number of KV tiles for this block

  const char* gkv = wsb + (size_t)bh * (NTILES * TILE_B);
  const char* gkt = wsb + KV_REGION + (size_t)bh * (NTILES * TILE_B);

  unsigned short* kvt = (unsigned short*)(smem + 2 * TILE_B);
  unsigned short* plw = (unsigned short*)(smem + 3 * TILE_B) + w * (16 * KB);

  // 512 threads stage a 16KB tile with 2 gl_lds16 each (wave-linear dest)
#define STAGE(DSTOFF, SRCBASE, KT)                                         \
  {                                                                        \
    char* dst_ = smem + (DSTOFF);                                          \
    const char* src_ = (SRCBASE) + (size_t)(KT) * TILE_B;                  \
    _Pragma("unroll")                                                      \
    for (int i_ = 0; i_ < 2; ++i_) {                                       \
      const int c_ = (i_ * 8 + w) * 1024;                                  \
      gl_lds16(src_ + c_ + lane * 16, dst_ + c_);                          \
    }                                                                      \
  }

  // prologue: stage both diagonal-region tiles + kvt of the first
  STAGE(0, gkv, 2 * q2);            // s=0 tile  (diag for waves 0-3)
  STAGE(TILE_B, gkv, 2 * q2 + 1);   // s=1 tile  (diag for waves 4-7)
  STAGE(2 * TILE_B, gkt, 2 * q2);   // kvt for s=0
  asm volatile("s_waitcnt vmcnt(0)" ::: "memory");
  __builtin_amdgcn_s_barrier();
  asm volatile("" ::: "memory");

  // Q fragments: wave w's rows live in buf0 (w<4) or buf1 (w>=4)
  const unsigned short* qbuf = (const unsigned short*)(smem + ((w >= 4) ? TILE_B : 0));
  bf16x8 qf[4];
#pragma unroll
  for (int c = 0; c < 4; ++c)
    qf[c] = ld256(qbuf, (16 * w + q15) & 63, c * 64 + g * 16);

  f32x4 acc[8];
#pragma unroll
  for (int dt = 0; dt < 8; ++dt) acc[dt] = (f32x4){0.f, 0.f, 0.f, 0.f};
  float mrun = -1e30f;   // RAW score domain
  float lrun = 0.f;

  for (int s = 0; s < nt; ++s) {
    if (s > 0) {  // kv(s) ready: drain all but the stages issued after it
      if (s + 1 < nt) asm volatile("s_waitcnt vmcnt(4)" ::: "memory");
      else            asm volatile("s_waitcnt vmcnt(2)" ::: "memory");
      __builtin_amdgcn_s_barrier();
      asm volatile("" ::: "memory");
    }
    const unsigned short* kv = (const unsigned short*)(smem + (s & 1) * TILE_B);
    const bool inactive = (s == 1) && (w < 4);   // fully-masked tile

    float pf[16];
    if (!inactive) {
      // S^T = K * Q^T : lane (g,q15) holds S[k = kt2*16+g*4+r][q = q15] (raw)
      float sv[16];
      __builtin_amdgcn_s_setprio(1);
#pragma unroll
      for (int kt2 = 0; kt2 < 4; ++kt2) {
        f32x4 st = (f32x4){0.f, 0.f, 0.f, 0.f};
#pragma unroll
        for (int c = 0; c < 4; ++c) {
          bf16x8 kf = ld256(kv, kt2 * 16 + q15, c * 64 + g * 16);
          st = mfma16(kf, qf[c], st);
        }
#pragma unroll
        for (int r = 0; r < 4; ++r) sv[kt2 * 4 + r] = st[r];
      }
      __builtin_amdgcn_s_setprio(0);

      if (s < 2 && ((s == 0) == (w < 4))) {  // diagonal tile for this wave
        const int qrel = (16 * w + q15) & 63;
#pragma unroll
        for (int kt2 = 0; kt2 < 4; ++kt2)
#pragma unroll
          for (int r = 0; r < 4; ++r)
            if (kt2 * 16 + g * 4 + r > qrel) sv[kt2 * 4 + r] = -1e30f;
      }

      // tree max over 16 in-lane values (one q-row), then across g-groups
      float m0 = fmaxf(fmaxf(sv[0], sv[1]), fmaxf(sv[2], sv[3]));
      float m1 = fmaxf(fmaxf(sv[4], sv[5]), fmaxf(sv[6], sv[7]));
      float m2 = fmaxf(fmaxf(sv[8], sv[9]), fmaxf(sv[10], sv[11]));
      float m3 = fmaxf(fmaxf(sv[12], sv[13]), fmaxf(sv[14], sv[15]));
      float tmax = fmaxf(fmaxf(m0, m1), fmaxf(m2, m3));
      tmax = fmaxf(tmax, __shfl_xor(tmax, 16));
      tmax = fmaxf(tmax, __shfl_xor(tmax, 32));

      if (__all(tmax <= mrun)) {
        // defer-max fast path: no max update, no rescale (P <= 1 guaranteed)
        const float nmc = -mrun * SCALE_LOG2E;
#pragma unroll
        for (int i = 0; i < 16; ++i) pf[i] = exp2f(fmaf(sv[i], SCALE_LOG2E, nmc));
      } else {
        const float mnew = fmaxf(mrun, tmax);
        const float al = exp2f((mrun - mnew) * SCALE_LOG2E);
        mrun = mnew;
        const float nmc = -mnew * SCALE_LOG2E;
#pragma unroll
        for (int i = 0; i < 16; ++i) pf[i] = exp2f(fmaf(sv[i], SCALE_LOG2E, nmc));
        lrun *= al;
        float ar[4];
#pragma unroll
        for (int r = 0; r < 4; ++r) ar[r] = __shfl(al, g * 4 + r);
#pragma unroll
        for (int dt = 0; dt < 8; ++dt)
#pragma unroll
          for (int r = 0; r < 4; ++r) acc[dt][r] *= ar[r];
      }

      // pairwise partial sum (reduced across g-groups at the end)
      float s01 = (pf[0] + pf[1]) + (pf[2] + pf[3]);
      float s23 = (pf[4] + pf[5]) + (pf[6] + pf[7]);
      float s45 = (pf[8] + pf[9]) + (pf[10] + pf[11]);
      float s67 = (pf[12] + pf[13]) + (pf[14] + pf[15]);
      lrun += (s01 + s23) + (s45 + s67);

      // P^T -> LDS as P[q][k] (bf16), 4x ds_write_b64
#pragma unroll
      for (int kt2 = 0; kt2 < 4; ++kt2) {
        u16x4 o = {f2bf(pf[kt2 * 4]), f2bf(pf[kt2 * 4 + 1]),
                   f2bf(pf[kt2 * 4 + 2]), f2bf(pf[kt2 * 4 + 3])};
        const int off = (q15 * 128 + kt2 * 32 + g * 8) ^ ((q15 & 7) << 4);
        *(u16x4*)((char*)plw + off) = o;
      }
      asm volatile("s_waitcnt lgkmcnt(0)" ::: "memory");
    }

    if (s > 0) {  // kvt(s) ready
      if (s + 1 < nt) asm volatile("s_waitcnt vmcnt(2)" ::: "memory");
      else            asm volatile("s_waitcnt vmcnt(0)" ::: "memory");
      __builtin_amdgcn_s_barrier();
      asm volatile("" ::: "memory");
    }

    if (!inactive) {
      // PV: acc[dt] += P(16xKB) * V(KBx16 slice dt)
      bf16x8 pa0 = ld128(plw, q15, g * 16);
      bf16x8 pa1 = ld128(plw, q15, 64 + g * 16);
      __builtin_amdgcn_s_setprio(1);
#pragma unroll
      for (int dt = 0; dt < 8; ++dt) {
        bf16x8 vb0 = ld128(kvt, dt * 16 + q15, g * 16);
        bf16x8 vb1 = ld128(kvt, dt * 16 + q15, 64 + g * 16);
        acc[dt] = mfma16(pa0, vb0, acc[dt]);
        acc[dt] = mfma16(pa1, vb1, acc[dt]);
      }
      __builtin_amdgcn_s_setprio(0);
    }

    // everyone done reading kv(s)/kvt(s); refill (async, lands across phases)
    __builtin_amdgcn_s_barrier();
    asm volatile("" ::: "memory");
    if (s + 1 < nt) STAGE(2 * TILE_B, gkt, (s == 0) ? (2 * q2 + 1) : (s - 1));
    if (s + 2 < nt) STAGE((s & 1) * TILE_B, gkv, s);
  }

  // combine the 4 g-groups' partial row sums
  lrun += __shfl_xor(lrun, 16);
  lrun += __shfl_xor(lrun, 32);

  const float inv = 1.f / lrun;
  float ir[4];
#pragma unroll
  for (int r = 0; r < 4; ++r) ir[r] = __shfl(inv, g * 4 + r);

  float* ob = out + ((size_t)b * TL + q0 + 16 * w) * TE + h * TD;
#pragma unroll
  for (int dt = 0; dt < 8; ++dt)
#pragma unroll
    for (int r = 0; r < 4; ++r)
      ob[(g * 4 + r) * TE + dt * 16 + q15] = acc[dt][r] * ir[r];
}

// ---------------- fallback (v1, self-contained staging) ---------------------
__global__ void __launch_bounds__(256)
evo_attn(const float* __restrict__ x, float* __restrict__ out) {
  __shared__ unsigned short kv[KB * TD];
  __shared__ unsigned short kvt[TD * KB];
  __shared__ unsigned short pl[4 * 16 * KB];

  const int t = threadIdx.x;
  const int lane = t & 63;
  const int w = t >> 6;
  const int g = lane >> 4;
  const int q15 = lane & 15;

  const int bh = blockIdx.x & 31;
  const int qt = 31 - (blockIdx.x >> 5);
  const int b = bh >> 4;
  const int h = bh & 15;
  const float* xb = x + (size_t)b * TL * TE + h * TD;
  const int q0 = qt * KB;

  stage_tile(xb + (size_t)q0 * TE, kv, kvt, t);
  __syncthreads();

  bf16x8 qf[4];
#pragma unroll
  for (int c = 0; c < 4; ++c)
    qf[c] = ld256(kv, 16 * w + q15, c * 64 + g * 16);

  f32x4 acc[8];
#pragma unroll
  for (int dt = 0; dt < 8; ++dt) acc[dt] = (f32x4){0.f, 0.f, 0.f, 0.f};
  float mrun = -1e30f;
  float lrun = 0.f;
  unsigned short* plw = pl + w * (16 * KB);

  for (int s = 0; s <= qt; ++s) {
    if (s > 0) {
      __syncthreads();
      stage_tile(xb + (size_t)(s - 1) * KB * TE, kv, kvt, t);
      __syncthreads();
    }
    float sv[16];
#pragma unroll
    for (int kt2 = 0; kt2 < 4; ++kt2) {
      f32x4 st = (f32x4){0.f, 0.f, 0.f, 0.f};
#pragma unroll
      for (int c = 0; c < 4; ++c) {
        bf16x8 kf = ld256(kv, kt2 * 16 + q15, c * 64 + g * 16);
        st = mfma16(kf, qf[c], st);
      }
#pragma unroll
      for (int r = 0; r < 4; ++r) sv[kt2 * 4 + r] = st[r] * SCALE_LOG2E;
    }
    if (s == 0) {
      const int qrel = 16 * w + q15;
#pragma unroll
      for (int kt2 = 0; kt2 < 4; ++kt2)
#pragma unroll
        for (int r = 0; r < 4; ++r)
          if (kt2 * 16 + g * 4 + r > qrel) sv[kt2 * 4 + r] = -1e30f;
    }
    float tmax = sv[0];
#pragma unroll
    for (int i = 1; i < 16; ++i) tmax = fmaxf(tmax, sv[i]);
    tmax = fmaxf(tmax, __shfl_xor(tmax, 16));
    tmax = fmaxf(tmax, __shfl_xor(tmax, 32));
    const float mnew = fmaxf(mrun, tmax);
    const float al = exp2f(mrun - mnew);
    mrun = mnew;
    float psum = 0.f;
    unsigned short pb[16];
#pragma unroll
    for (int i = 0; i < 16; ++i) {
      const float p = exp2f(sv[i] - mnew);
      psum += p;
      pb[i] = f2bf(p);
    }
    lrun = lrun * al + psum;
#pragma unroll
    for (int kt2 = 0; kt2 < 4; ++kt2) {
      u16x4 o = {pb[kt2 * 4], pb[kt2 * 4 + 1], pb[kt2 * 4 + 2], pb[kt2 * 4 + 3]};
      const int off = (q15 * 128 + kt2 * 32 + g * 8) ^ ((q15 & 7) << 4);
      *(u16x4*)((char*)plw + off) = o;
    }
    asm volatile("s_waitcnt lgkmcnt(0)" ::: "memory");
    float ar[4];
#pragma unroll
    for (int r = 0; r < 4; ++r) ar[r] = __shfl(al, g * 4 + r);
#pragma unroll
    for (int dt = 0; dt < 8; ++dt)
#pragma unroll
      for (int r = 0; r < 4; ++r) acc[dt][r] *= ar[r];
    bf16x8 pa0 = ld128(plw, q15, g * 16);
    bf16x8 pa1 = ld128(plw, q15, 64 + g * 16);
#pragma unroll
    for (int dt = 0; dt < 8; ++dt) {
      bf16x8 vb0 = ld128(kvt, dt * 16 + q15, g * 16);
      bf16x8 vb1 = ld128(kvt, dt * 16 + q15, 64 + g * 16);
      acc[dt] = mfma16(pa0, vb0, acc[dt]);
      acc[dt] = mfma16(pa1, vb1, acc[dt]);
    }
  }

  lrun += __shfl_xor(lrun, 16);
  lrun += __shfl_xor(lrun, 32);
  const float inv = 1.f / lrun;
  float ir[4];
#pragma unroll
  for (int r = 0; r < 4; ++r) ir[r] = __shfl(inv, g * 4 + r);
  float* ob = out + ((size_t)b * TL + q0 + 16 * w) * TE + h * TD;
#pragma unroll
  for (int dt = 0; dt < 8; ++dt)
#pragma unroll
    for (int r = 0; r < 4; ++r)
      ob[(g * 4 + r) * TE + dt * 16 + q15] = acc[dt][r] * ir[r];
}

extern "C" void kernel_launch(void* const* d_in, const int* in_sizes, int n_in,
                              void* d_out, int out_size, void* d_ws, size_t ws_size,
                              hipStream_t stream) {
  const float* x = (const float*)d_in[0];
  float* out = (float*)d_out;
  (void)in_sizes; (void)n_in; (void)out_size;
  if (ws_size >= (size_t)WS_NEED) {
    char* wsb = (char*)d_ws;
    prepack<<<dim3(1024), dim3(256), 0, stream>>>(x, wsb);
    evo_attn2<<<dim3(512), dim3(512), 0, stream>>>(wsb, out);
  } else {
    evo_attn<<<dim3(1024), dim3(256), 0, stream>>>(x, out);
  }
}

// Round 6
// 141.264 us; speedup vs baseline: 1.4979x; 1.4979x over previous
//
#include <hip/hip_runtime.h>
#include <hip/hip_bf16.h>

// EvoAttn: causal self-attention with Q=K=V = x.reshape(B,L,H,D).
// B=2 H=16 L=2048 D=128, fp32 in/out, bf16 MFMA compute.
// v6 = v5 with the STAGE bug fixed: global_load_lds LDS dest is wave-uniform
//      base + lane*16, so each wave MUST get its own 1KB dest chunk.

#define TL 2048
#define TE 2048
#define TD 128
#define KB 64
#define NTILES 32                          // TL / KB
#define TILE_B 16384                       // 64*128*2 bytes
#define KV_REGION (32 * NTILES * TILE_B)   // 16 MB per layout
#define WS_NEED (2u * (unsigned)KV_REGION) // 32 MB

typedef __attribute__((ext_vector_type(8))) short bf16x8;
typedef __attribute__((ext_vector_type(4))) float f32x4;
typedef __attribute__((ext_vector_type(8))) unsigned short u16x8;
typedef __attribute__((ext_vector_type(4))) unsigned short u16x4;

// (1/sqrt(128)) * log2(e)
#define SCALE_LOG2E 0.12751879f

__device__ __forceinline__ unsigned short f2bf(float f) {
  __hip_bfloat16 h = __float2bfloat16(f);
  return __builtin_bit_cast(unsigned short, h);
}

__device__ __forceinline__ f32x4 mfma16(bf16x8 a, bf16x8 b, f32x4 c) {
  return __builtin_amdgcn_mfma_f32_16x16x32_bf16(a, b, c, 0, 0, 0);
}

__device__ __forceinline__ void gl_lds16(const void* g, void* l) {
  __builtin_amdgcn_global_load_lds(
      (__attribute__((address_space(1))) void*)(g),
      (__attribute__((address_space(3))) void*)(l), 16, 0, 0);
}

// kv: [64 rows k][128 d] bf16, row stride 256B, byte ^= (k&7)<<4
// kvt:[128 rows d][64 k] bf16, row stride 128B, byte ^= (d&7)<<4
__device__ __forceinline__ void stage_tile(const float* __restrict__ src,
                                           unsigned short* kv, unsigned short* kvt,
                                           int t) {
  const int kr = (t >> 4) << 2;
  const int d0 = (t & 15) << 3;
  unsigned short c[4][8];
#pragma unroll
  for (int rr = 0; rr < 4; ++rr) {
    const float* p = src + (kr + rr) * TE + d0;
    const float4 a = *(const float4*)p;
    const float4 b = *(const float4*)(p + 4);
    c[rr][0] = f2bf(a.x); c[rr][1] = f2bf(a.y); c[rr][2] = f2bf(a.z); c[rr][3] = f2bf(a.w);
    c[rr][4] = f2bf(b.x); c[rr][5] = f2bf(b.y); c[rr][6] = f2bf(b.z); c[rr][7] = f2bf(b.w);
  }
#pragma unroll
  for (int rr = 0; rr < 4; ++rr) {
    const int r = kr + rr;
    u16x8 o = {c[rr][0], c[rr][1], c[rr][2], c[rr][3],
               c[rr][4], c[rr][5], c[rr][6], c[rr][7]};
    const int off = (r * 256 + d0 * 2) ^ ((r & 7) << 4);
    *(u16x8*)((char*)kv + off) = o;
  }
#pragma unroll
  for (int cc = 0; cc < 8; ++cc) {
    const int d = d0 + cc;
    u16x4 o = {c[0][cc], c[1][cc], c[2][cc], c[3][cc]};
    const int off = (d * 128 + kr * 2) ^ ((d & 7) << 4);
    *(u16x4*)((char*)kvt + off) = o;
  }
}

__device__ __forceinline__ bf16x8 ld256(const unsigned short* base, int row, int inrow) {
  const int off = (row * 256 + inrow) ^ ((row & 7) << 4);
  return *(const bf16x8*)((const char*)base + off);
}
__device__ __forceinline__ bf16x8 ld128(const unsigned short* base, int row, int inrow) {
  const int off = (row * 128 + inrow) ^ ((row & 7) << 4);
  return *(const bf16x8*)((const char*)base + off);
}

// ---------------- pre-pass: x (f32) -> pre-swizzled bf16 tile images in ws --
__global__ void __launch_bounds__(256)
prepack(const float* __restrict__ x, char* __restrict__ wsb) {
  __shared__ unsigned short kv[KB * TD];
  __shared__ unsigned short kvt[TD * KB];
  const int bid = blockIdx.x;            // bh*32 + kt
  const int kt = bid & 31;
  const int bh = bid >> 5;
  const int b = bh >> 4;
  const int h = bh & 15;
  const float* src = x + (size_t)b * TL * TE + h * TD + (size_t)kt * KB * TE;
  stage_tile(src, kv, kvt, threadIdx.x);
  __syncthreads();
  char* gkv = wsb + (size_t)bid * TILE_B;
  char* gkt = wsb + KV_REGION + (size_t)bid * TILE_B;
  const char* lv = (const char*)kv;
  const char* lt = (const char*)kvt;
  const int t = threadIdx.x;
#pragma unroll
  for (int i = 0; i < 4; ++i) {
    *(u16x8*)(gkv + t * 64 + i * 16) = *(const u16x8*)(lv + t * 64 + i * 16);
    *(u16x8*)(gkt + t * 64 + i * 16) = *(const u16x8*)(lt + t * 64 + i * 16);
  }
}

// ---------------- main attention kernel (4 waves x 32 q-rows, QB=128) -------
__global__ void __launch_bounds__(256)
evo_attn2(const char* __restrict__ wsb, float* __restrict__ out) {
  // buf0 (16KB) | buf1 (16KB) | kvt (16KB) | pl (4 waves x 4KB) = 64 KB
  __shared__ char smem[4 * TILE_B];

  const int t = threadIdx.x;
  const int lane = t & 63;
  const int w = t >> 6;        // wave 0..3, owns q rows [q0+32w, q0+32w+32)
  const int g = lane >> 4;
  const int q15 = lane & 15;

  const int v = blockIdx.x;              // 512 blocks
  const int bh = (v >> 4) & 31;
  // zigzag: consecutive-pair AND +256-pair work sums ~constant
  const int ZIG[16] = {15, 0, 13, 2, 11, 4, 9, 6, 8, 7, 10, 5, 12, 3, 14, 1};
  const int q2 = ZIG[(v + (v >> 8)) & 15];
  const int b = bh >> 4;
  const int h = bh & 15;
  const int q0 = q2 * 128;
  const int nt = 2 * q2 + 2;             // KV tiles for this block

  const char* gkv = wsb + (size_t)bh * (NTILES * TILE_B);
  const char* gkt = wsb + KV_REGION + (size_t)bh * (NTILES * TILE_B);

  unsigned short* kvt = (unsigned short*)(smem + 2 * TILE_B);
  unsigned short* plw = (unsigned short*)(smem + 3 * TILE_B) + w * (32 * KB);

  // 256 threads stage one 16KB tile: 4 x gl_lds16 per thread.
  // HW: LDS dest = wave-uniform base + lane*16 -> each wave needs its own
  // 1KB dest chunk ((t>>6)*1024); global src carries the full per-lane addr.
#define STAGE(DSTOFF, SRCBASE, KT)                                         \
  {                                                                        \
    char* dst_ = smem + (DSTOFF) + (t >> 6) * 1024;                        \
    const char* src_ = (SRCBASE) + (size_t)(KT) * TILE_B + t * 16;         \
    _Pragma("unroll")                                                      \
    for (int i_ = 0; i_ < 4; ++i_) {                                       \
      gl_lds16(src_ + i_ * 4096, dst_ + i_ * 4096);                        \
    }                                                                      \
  }

  // tile index for step s
#define TIDX(S) (((S) < 2) ? (2 * q2 + (S)) : ((S)-2))

  // prologue: both diagonal-region kv tiles + kvt of the first
  STAGE(0, gkv, 2 * q2);
  STAGE(TILE_B, gkv, 2 * q2 + 1);
  STAGE(2 * TILE_B, gkt, 2 * q2);
  asm volatile("s_waitcnt vmcnt(0)" ::: "memory");
  __builtin_amdgcn_s_barrier();
  asm volatile("" ::: "memory");

  // Q fragments: wave w rows [32w,32w+32): buf0 holds rows 0-63, buf1 64-127
  const unsigned short* qbuf =
      (const unsigned short*)(smem + ((w >= 2) ? TILE_B : 0));
  bf16x8 qf[2][4];
#pragma unroll
  for (int qs = 0; qs < 2; ++qs)
#pragma unroll
    for (int c = 0; c < 4; ++c)
      qf[qs][c] = ld256(qbuf, 32 * (w & 1) + 16 * qs + q15, c * 64 + g * 16);

  f32x4 acc[2][8];
#pragma unroll
  for (int qs = 0; qs < 2; ++qs)
#pragma unroll
    for (int dt = 0; dt < 8; ++dt) acc[qs][dt] = (f32x4){0.f, 0.f, 0.f, 0.f};
  float mrun[2] = {-1e30f, -1e30f};   // raw score domain
  float lrun[2] = {0.f, 0.f};

  for (int s = 0; s < nt; ++s) {
    if (s >= 2) {  // kv(s) ready (kv(0),kv(1) prologue-drained)
      if (s + 1 < nt) asm volatile("s_waitcnt vmcnt(8)" ::: "memory");
      else            asm volatile("s_waitcnt vmcnt(4)" ::: "memory");
      __builtin_amdgcn_s_barrier();
      asm volatile("" ::: "memory");
    }
    const unsigned short* kv = (const unsigned short*)(smem + (s & 1) * TILE_B);
    const bool inactive = (s == 1) && (w < 2);   // fully-masked tile

    float pf[2][16];
    if (!inactive) {
      // S^T = K * Q^T : lane (g,q15) holds, per qs,
      // S[k = kt2*16+g*4+r][q-row = 32w+16qs+q15] (raw scores)
      __builtin_amdgcn_s_setprio(1);
#pragma unroll
      for (int kt2 = 0; kt2 < 4; ++kt2) {
        f32x4 st0 = (f32x4){0.f, 0.f, 0.f, 0.f};
        f32x4 st1 = (f32x4){0.f, 0.f, 0.f, 0.f};
#pragma unroll
        for (int c = 0; c < 4; ++c) {
          bf16x8 kf = ld256(kv, kt2 * 16 + q15, c * 64 + g * 16);
          st0 = mfma16(kf, qf[0][c], st0);
          st1 = mfma16(kf, qf[1][c], st1);
        }
#pragma unroll
        for (int r = 0; r < 4; ++r) {
          pf[0][kt2 * 4 + r] = st0[r];
          pf[1][kt2 * 4 + r] = st1[r];
        }
      }
      __builtin_amdgcn_s_setprio(0);

      if (s < 2) {  // causal mask if this tile is diagonal for this wave
        const int qrb = 32 * w - 64 * s;
        if (qrb >= 0 && qrb < 64) {
#pragma unroll
          for (int qs = 0; qs < 2; ++qs) {
            const int qrel = qrb + 16 * qs + q15;
#pragma unroll
            for (int kt2 = 0; kt2 < 4; ++kt2)
#pragma unroll
              for (int r = 0; r < 4; ++r)
                if (kt2 * 16 + g * 4 + r > qrel) pf[qs][kt2 * 4 + r] = -1e30f;
          }
        }
      }

      // online softmax (defer-max): per-qs row max across 16 in-lane + groups
      float tmax[2];
#pragma unroll
      for (int qs = 0; qs < 2; ++qs) {
        float m0 = fmaxf(fmaxf(pf[qs][0], pf[qs][1]), fmaxf(pf[qs][2], pf[qs][3]));
        float m1 = fmaxf(fmaxf(pf[qs][4], pf[qs][5]), fmaxf(pf[qs][6], pf[qs][7]));
        float m2 = fmaxf(fmaxf(pf[qs][8], pf[qs][9]), fmaxf(pf[qs][10], pf[qs][11]));
        float m3 = fmaxf(fmaxf(pf[qs][12], pf[qs][13]), fmaxf(pf[qs][14], pf[qs][15]));
        float tm = fmaxf(fmaxf(m0, m1), fmaxf(m2, m3));
        tm = fmaxf(tm, __shfl_xor(tm, 16));
        tm = fmaxf(tm, __shfl_xor(tm, 32));
        tmax[qs] = tm;
      }

      if (__all((tmax[0] <= mrun[0]) && (tmax[1] <= mrun[1]))) {
        // fast path: no max update, no rescale (P <= 1 guaranteed)
#pragma unroll
        for (int qs = 0; qs < 2; ++qs) {
          const float nmc = -mrun[qs] * SCALE_LOG2E;
#pragma unroll
          for (int i = 0; i < 16; ++i)
            pf[qs][i] = exp2f(fmaf(pf[qs][i], SCALE_LOG2E, nmc));
        }
      } else {
#pragma unroll
        for (int qs = 0; qs < 2; ++qs) {
          const float mnew = fmaxf(mrun[qs], tmax[qs]);
          const float al = exp2f((mrun[qs] - mnew) * SCALE_LOG2E);
          mrun[qs] = mnew;
          const float nmc = -mnew * SCALE_LOG2E;
#pragma unroll
          for (int i = 0; i < 16; ++i)
            pf[qs][i] = exp2f(fmaf(pf[qs][i], SCALE_LOG2E, nmc));
          lrun[qs] *= al;
          float ar[4];
#pragma unroll
          for (int r = 0; r < 4; ++r) ar[r] = __shfl(al, g * 4 + r);
#pragma unroll
          for (int dt = 0; dt < 8; ++dt)
#pragma unroll
            for (int r = 0; r < 4; ++r) acc[qs][dt][r] *= ar[r];
        }
      }

#pragma unroll
      for (int qs = 0; qs < 2; ++qs) {
        float s01 = (pf[qs][0] + pf[qs][1]) + (pf[qs][2] + pf[qs][3]);
        float s23 = (pf[qs][4] + pf[qs][5]) + (pf[qs][6] + pf[qs][7]);
        float s45 = (pf[qs][8] + pf[qs][9]) + (pf[qs][10] + pf[qs][11]);
        float s67 = (pf[qs][12] + pf[qs][13]) + (pf[qs][14] + pf[qs][15]);
        lrun[qs] += (s01 + s23) + (s45 + s67);
      }

      // P -> LDS as P[q(32)][k(64)] bf16 (pl row stride 128B, swizzled)
#pragma unroll
      for (int qs = 0; qs < 2; ++qs)
#pragma unroll
        for (int kt2 = 0; kt2 < 4; ++kt2) {
          u16x4 o = {f2bf(pf[qs][kt2 * 4]), f2bf(pf[qs][kt2 * 4 + 1]),
                     f2bf(pf[qs][kt2 * 4 + 2]), f2bf(pf[qs][kt2 * 4 + 3])};
          const int off =
              ((16 * qs + q15) * 128 + kt2 * 32 + g * 8) ^ ((q15 & 7) << 4);
          *(u16x4*)((char*)plw + off) = o;
        }
      asm volatile("s_waitcnt lgkmcnt(0)" ::: "memory");
    }

    if (s >= 1) {  // kvt(s) ready
      if (s + 1 < nt) asm volatile("s_waitcnt vmcnt(4)" ::: "memory");
      else            asm volatile("s_waitcnt vmcnt(0)" ::: "memory");
      __builtin_amdgcn_s_barrier();
      asm volatile("" ::: "memory");
    }

    if (!inactive) {
      // PV: acc[qs][dt] += P(16xKB) * V(KBx16 slice dt); V frags shared by qs
      bf16x8 pa[2][2];
#pragma unroll
      for (int qs = 0; qs < 2; ++qs) {
        pa[qs][0] = ld128(plw, 16 * qs + q15, g * 16);
        pa[qs][1] = ld128(plw, 16 * qs + q15, 64 + g * 16);
      }
      __builtin_amdgcn_s_setprio(1);
#pragma unroll
      for (int dt = 0; dt < 8; ++dt) {
        bf16x8 vb0 = ld128(kvt, dt * 16 + q15, g * 16);
        bf16x8 vb1 = ld128(kvt, dt * 16 + q15, 64 + g * 16);
#pragma unroll
        for (int qs = 0; qs < 2; ++qs) {
          acc[qs][dt] = mfma16(pa[qs][0], vb0, acc[qs][dt]);
          acc[qs][dt] = mfma16(pa[qs][1], vb1, acc[qs][dt]);
        }
      }
      __builtin_amdgcn_s_setprio(0);
    }

    // all waves done reading kv(s)/kvt(s); refill (async, lands next phases)
    __builtin_amdgcn_s_barrier();
    asm volatile("" ::: "memory");
    if (s + 1 < nt) STAGE(2 * TILE_B, gkt, TIDX(s + 1));
    if (s + 2 < nt) STAGE((s & 1) * TILE_B, gkv, TIDX(s + 2));
  }

  // combine the 4 g-groups' partial row sums
#pragma unroll
  for (int qs = 0; qs < 2; ++qs) {
    lrun[qs] += __shfl_xor(lrun[qs], 16);
    lrun[qs] += __shfl_xor(lrun[qs], 32);
  }

  float* ob = out + ((size_t)b * TL + q0 + 32 * w) * TE + h * TD;
#pragma unroll
  for (int qs = 0; qs < 2; ++qs) {
    const float inv = 1.f / lrun[qs];
    float ir[4];
#pragma unroll
    for (int r = 0; r < 4; ++r) ir[r] = __shfl(inv, g * 4 + r);
#pragma unroll
    for (int dt = 0; dt < 8; ++dt)
#pragma unroll
      for (int r = 0; r < 4; ++r)
        ob[(16 * qs + g * 4 + r) * TE + dt * 16 + q15] = acc[qs][dt][r] * ir[r];
  }
}

// ---------------- fallback (v1, self-contained staging) ---------------------
__global__ void __launch_bounds__(256)
evo_attn(const float* __restrict__ x, float* __restrict__ out) {
  __shared__ unsigned short kv[KB * TD];
  __shared__ unsigned short kvt[TD * KB];
  __shared__ unsigned short pl[4 * 16 * KB];

  const int t = threadIdx.x;
  const int lane = t & 63;
  const int w = t >> 6;
  const int g = lane >> 4;
  const int q15 = lane & 15;

  const int bh = blockIdx.x & 31;
  const int qt = 31 - (blockIdx.x >> 5);
  const int b = bh >> 4;
  const int h = bh & 15;
  const float* xb = x + (size_t)b * TL * TE + h * TD;
  const int q0 = qt * KB;

  stage_tile(xb + (size_t)q0 * TE, kv, kvt, t);
  __syncthreads();

  bf16x8 qf[4];
#pragma unroll
  for (int c = 0; c < 4; ++c)
    qf[c] = ld256(kv, 16 * w + q15, c * 64 + g * 16);

  f32x4 acc[8];
#pragma unroll
  for (int dt = 0; dt < 8; ++dt) acc[dt] = (f32x4){0.f, 0.f, 0.f, 0.f};
  float mrun = -1e30f;
  float lrun = 0.f;
  unsigned short* plw = pl + w * (16 * KB);

  for (int s = 0; s <= qt; ++s) {
    if (s > 0) {
      __syncthreads();
      stage_tile(xb + (size_t)(s - 1) * KB * TE, kv, kvt, t);
      __syncthreads();
    }
    float sv[16];
#pragma unroll
    for (int kt2 = 0; kt2 < 4; ++kt2) {
      f32x4 st = (f32x4){0.f, 0.f, 0.f, 0.f};
#pragma unroll
      for (int c = 0; c < 4; ++c) {
        bf16x8 kf = ld256(kv, kt2 * 16 + q15, c * 64 + g * 16);
        st = mfma16(kf, qf[c], st);
      }
#pragma unroll
      for (int r = 0; r < 4; ++r) sv[kt2 * 4 + r] = st[r] * SCALE_LOG2E;
    }
    if (s == 0) {
      const int qrel = 16 * w + q15;
#pragma unroll
      for (int kt2 = 0; kt2 < 4; ++kt2)
#pragma unroll
        for (int r = 0; r < 4; ++r)
          if (kt2 * 16 + g * 4 + r > qrel) sv[kt2 * 4 + r] = -1e30f;
    }
    float tmax = sv[0];
#pragma unroll
    for (int i = 1; i < 16; ++i) tmax = fmaxf(tmax, sv[i]);
    tmax = fmaxf(tmax, __shfl_xor(tmax, 16));
    tmax = fmaxf(tmax, __shfl_xor(tmax, 32));
    const float mnew = fmaxf(mrun, tmax);
    const float al = exp2f(mrun - mnew);
    mrun = mnew;
    float psum = 0.f;
    unsigned short pb[16];
#pragma unroll
    for (int i = 0; i < 16; ++i) {
      const float p = exp2f(sv[i] - mnew);
      psum += p;
      pb[i] = f2bf(p);
    }
    lrun = lrun * al + psum;
#pragma unroll
    for (int kt2 = 0; kt2 < 4; ++kt2) {
      u16x4 o = {pb[kt2 * 4], pb[kt2 * 4 + 1], pb[kt2 * 4 + 2], pb[kt2 * 4 + 3]};
      const int off = (q15 * 128 + kt2 * 32 + g * 8) ^ ((q15 & 7) << 4);
      *(u16x4*)((char*)plw + off) = o;
    }
    asm volatile("s_waitcnt lgkmcnt(0)" ::: "memory");
    float ar[4];
#pragma unroll
    for (int r = 0; r < 4; ++r) ar[r] = __shfl(al, g * 4 + r);
#pragma unroll
    for (int dt = 0; dt < 8; ++dt)
#pragma unroll
      for (int r = 0; r < 4; ++r) acc[dt][r] *= ar[r];
    bf16x8 pa0 = ld128(plw, q15, g * 16);
    bf16x8 pa1 = ld128(plw, q15, 64 + g * 16);
#pragma unroll
    for (int dt = 0; dt < 8; ++dt) {
      bf16x8 vb0 = ld128(kvt, dt * 16 + q15, g * 16);
      bf16x8 vb1 = ld128(kvt, dt * 16 + q15, 64 + g * 16);
      acc[dt] = mfma16(pa0, vb0, acc[dt]);
      acc[dt] = mfma16(pa1, vb1, acc[dt]);
    }
  }

  lrun += __shfl_xor(lrun, 16);
  lrun += __shfl_xor(lrun, 32);
  const float inv = 1.f / lrun;
  float ir[4];
#pragma unroll
  for (int r = 0; r < 4; ++r) ir[r] = __shfl(inv, g * 4 + r);
  float* ob = out + ((size_t)b * TL + q0 + 16 * w) * TE + h * TD;
#pragma unroll
  for (int dt = 0; dt < 8; ++dt)
#pragma unroll
    for (int r = 0; r < 4; ++r)
      ob[(g * 4 + r) * TE + dt * 16 + q15] = acc[dt][r] * ir[r];
}

extern "C" void kernel_launch(void* const* d_in, const int* in_sizes, int n_in,
                              void* d_out, int out_size, void* d_ws, size_t ws_size,
                              hipStream_t stream) {
  const float* x = (const float*)d_in[0];
  float* out = (float*)d_out;
  (void)in_sizes; (void)n_in; (void)out_size;
  if (ws_size >= (size_t)WS_NEED) {
    char* wsb = (char*)d_ws;
    prepack<<<dim3(1024), dim3(256), 0, stream>>>(x, wsb);
    evo_attn2<<<dim3(512), dim3(256), 0, stream>>>(wsb, out);
  } else {
    evo_attn<<<dim3(1024), dim3(256), 0, stream>>>(x, out);
  }
}

// Round 7
// 137.858 us; speedup vs baseline: 1.5349x; 1.0247x over previous
//
#include <hip/hip_runtime.h>
#include <hip/hip_bf16.h>

// EvoAttn: causal self-attention with Q=K=V = x.reshape(B,L,H,D).
// B=2 H=16 L=2048 D=128, fp32 in/out, bf16 MFMA compute.
// v7: V fragments global->register (drop kvt LDS tile; fragment-order prepack),
//     48KB LDS -> 3 blocks/CU, 2 barriers/step, no setprio.

#define TL 2048
#define TE 2048
#define TD 128
#define KB 64
#define NTILES 32                          // TL / KB
#define TILE_B 16384                       // 64*128*2 bytes
#define KV_REGION (32 * NTILES * TILE_B)   // 16 MB per layout
#define WS_NEED (2u * (unsigned)KV_REGION) // 32 MB

typedef __attribute__((ext_vector_type(8))) short bf16x8;
typedef __attribute__((ext_vector_type(4))) float f32x4;
typedef __attribute__((ext_vector_type(8))) unsigned short u16x8;
typedef __attribute__((ext_vector_type(4))) unsigned short u16x4;

// (1/sqrt(128)) * log2(e)
#define SCALE_LOG2E 0.12751879f

__device__ __forceinline__ unsigned short f2bf(float f) {
  __hip_bfloat16 h = __float2bfloat16(f);
  return __builtin_bit_cast(unsigned short, h);
}

__device__ __forceinline__ f32x4 mfma16(bf16x8 a, bf16x8 b, f32x4 c) {
  return __builtin_amdgcn_mfma_f32_16x16x32_bf16(a, b, c, 0, 0, 0);
}

__device__ __forceinline__ void gl_lds16(const void* g, void* l) {
  __builtin_amdgcn_global_load_lds(
      (__attribute__((address_space(1))) void*)(g),
      (__attribute__((address_space(3))) void*)(l), 16, 0, 0);
}

__device__ __forceinline__ bf16x8 ld256(const unsigned short* base, int row, int inrow) {
  const int off = (row * 256 + inrow) ^ ((row & 7) << 4);
  return *(const bf16x8*)((const char*)base + off);
}
__device__ __forceinline__ bf16x8 ld128(const unsigned short* base, int row, int inrow) {
  const int off = (row * 128 + inrow) ^ ((row & 7) << 4);
  return *(const bf16x8*)((const char*)base + off);
}

// kv region: per-tile LDS byte image [64 k][128 d] bf16, byte ^= (k&7)<<4.
// kvt region: per-tile FRAGMENT-ORDER V: 16B frag (half,dt,g,q15) at byte
//   ((half*8+dt)*64 + g*16 + q15)*16, holding V[k=half*32+g*8+j][d=dt*16+q15].
__global__ void __launch_bounds__(256)
prepack(const float* __restrict__ x, char* __restrict__ wsb) {
  const int bid = blockIdx.x;            // bh*32 + kt
  const int kt = bid & 31;
  const int bh = bid >> 5;
  const int b = bh >> 4;
  const int h = bh & 15;
  const float* src = x + (size_t)b * TL * TE + h * TD + (size_t)kt * KB * TE;
  const int t = threadIdx.x;
  const int kr = (t >> 4) << 2;          // 4 consecutive k-rows
  const int d0 = (t & 15) << 3;          // 8 d-cols
  unsigned short c[4][8];
#pragma unroll
  for (int rr = 0; rr < 4; ++rr) {
    const float* p = src + (kr + rr) * TE + d0;
    const float4 a = *(const float4*)p;
    const float4 bb = *(const float4*)(p + 4);
    c[rr][0] = f2bf(a.x);  c[rr][1] = f2bf(a.y);  c[rr][2] = f2bf(a.z);  c[rr][3] = f2bf(a.w);
    c[rr][4] = f2bf(bb.x); c[rr][5] = f2bf(bb.y); c[rr][6] = f2bf(bb.z); c[rr][7] = f2bf(bb.w);
  }
  // K-layout tile (LDS image, swizzled)
  char* gkv = wsb + (size_t)bid * TILE_B;
#pragma unroll
  for (int rr = 0; rr < 4; ++rr) {
    const int r = kr + rr;
    u16x8 o = {c[rr][0], c[rr][1], c[rr][2], c[rr][3],
               c[rr][4], c[rr][5], c[rr][6], c[rr][7]};
    const int off = (r * 256 + d0 * 2) ^ ((r & 7) << 4);
    *(u16x8*)(gkv + off) = o;
  }
  // V-layout tile (fragment order for direct global->reg loads)
  char* gkt = wsb + KV_REGION + (size_t)bid * TILE_B;
  const int half = kr >> 5;
  const int g = (kr >> 3) & 3;
  const int j0 = kr & 7;                 // 0 or 4
#pragma unroll
  for (int cc = 0; cc < 8; ++cc) {
    const int d = d0 + cc;
    u16x4 o = {c[0][cc], c[1][cc], c[2][cc], c[3][cc]};   // k = kr..kr+3
    const int off = (((half * 8 + (d >> 4)) * 64 + g * 16 + (d & 15)) << 4) + j0 * 2;
    *(u16x4*)(gkt + off) = o;
  }
}

// ---------------- main attention kernel (4 waves x 32 q-rows, QB=128) -------
__global__ void __launch_bounds__(256)
evo_attn2(const char* __restrict__ wsb, float* __restrict__ out) {
  // buf0 (16KB) | buf1 (16KB) | pl (4 waves x 4KB) = 48 KB -> 3 blocks/CU
  __shared__ char smem[3 * TILE_B];

  const int t = threadIdx.x;
  const int lane = t & 63;
  const int w = t >> 6;        // wave 0..3, owns q rows [q0+32w, q0+32w+32)
  const int g = lane >> 4;
  const int q15 = lane & 15;

  const int v = blockIdx.x;              // 512 blocks
  const int bh = (v >> 4) & 31;
  const int ZIG[16] = {15, 0, 13, 2, 11, 4, 9, 6, 8, 7, 10, 5, 12, 3, 14, 1};
  const int q2 = ZIG[(v + (v >> 8)) & 15];
  const int b = bh >> 4;
  const int h = bh & 15;
  const int q0 = q2 * 128;
  const int nt = 2 * q2 + 2;             // KV tiles for this block

  const char* gkv = wsb + (size_t)bh * (NTILES * TILE_B);
  const char* gkt = wsb + KV_REGION + (size_t)bh * (NTILES * TILE_B);
  unsigned short* plw = (unsigned short*)(smem + 2 * TILE_B) + w * (32 * KB);

  // 256 threads stage one 16KB K-tile: 4 gl_lds16/thread; LDS dest is
  // wave-uniform base + lane*16 -> per-wave 1KB chunk (t>>6)*1024.
#define STAGE(BUFI, KT)                                                    \
  {                                                                        \
    char* dst_ = smem + (BUFI) * TILE_B + (t >> 6) * 1024;                 \
    const char* src_ = gkv + (size_t)(KT) * TILE_B + t * 16;               \
    _Pragma("unroll")                                                      \
    for (int i_ = 0; i_ < 4; ++i_) {                                       \
      gl_lds16(src_ + i_ * 4096, dst_ + i_ * 4096);                        \
    }                                                                      \
  }

#define TIDX(S) (((S) < 2) ? (2 * q2 + (S)) : ((S)-2))

  // V fragments for one tile, global->register (16 x coalesced 16B loads)
  bf16x8 vbr[2][8];
#define VLOAD(S)                                                           \
  {                                                                        \
    const char* vt_ = gkt + (size_t)TIDX(S) * TILE_B + lane * 16;          \
    _Pragma("unroll")                                                      \
    for (int h_ = 0; h_ < 2; ++h_)                                         \
      _Pragma("unroll")                                                    \
      for (int d_ = 0; d_ < 8; ++d_)                                       \
        vbr[h_][d_] = *(const bf16x8*)(vt_ + (h_ * 8 + d_) * 1024);        \
  }

  // prologue: both diagonal-region K-tiles + V frags of step 0
  STAGE(0, 2 * q2);
  STAGE(1, 2 * q2 + 1);
  VLOAD(0);
  asm volatile("s_waitcnt vmcnt(16)" ::: "memory");   // both STAGEs done
  __builtin_amdgcn_s_barrier();
  asm volatile("" ::: "memory");

  // Q fragments: wave w rows [32w,32w+32): buf0 rows 0-63, buf1 rows 64-127
  const unsigned short* qbuf =
      (const unsigned short*)(smem + ((w >= 2) ? TILE_B : 0));
  bf16x8 qf[2][4];
#pragma unroll
  for (int qs = 0; qs < 2; ++qs)
#pragma unroll
    for (int c = 0; c < 4; ++c)
      qf[qs][c] = ld256(qbuf, 32 * (w & 1) + 16 * qs + q15, c * 64 + g * 16);

  f32x4 acc[2][8];
#pragma unroll
  for (int qs = 0; qs < 2; ++qs)
#pragma unroll
    for (int dt = 0; dt < 8; ++dt) acc[qs][dt] = (f32x4){0.f, 0.f, 0.f, 0.f};
  float mrun[2] = {-1e30f, -1e30f};   // raw score domain
  float lrun[2] = {0.f, 0.f};

  for (int s = 0; s < nt; ++s) {
    if (s > 0) {  // A: kv(s) ready. outstanding = vb(s)[16] (+ kv(s+1)[4])
      if (s + 1 < nt) asm volatile("s_waitcnt vmcnt(20)" ::: "memory");
      else            asm volatile("s_waitcnt vmcnt(16)" ::: "memory");
      __builtin_amdgcn_s_barrier();
      asm volatile("" ::: "memory");
    }
    const unsigned short* kv = (const unsigned short*)(smem + (s & 1) * TILE_B);
    const bool inactive = (s == 1) && (w < 2);   // fully-masked tile

    float pf[2][16];
    if (!inactive) {
      // B: S^T = K * Q^T : lane (g,q15) holds, per qs,
      // S[k = kt2*16+g*4+r][q-row = 32w+16qs+q15] (raw scores)
#pragma unroll
      for (int kt2 = 0; kt2 < 4; ++kt2) {
        f32x4 st0 = (f32x4){0.f, 0.f, 0.f, 0.f};
        f32x4 st1 = (f32x4){0.f, 0.f, 0.f, 0.f};
#pragma unroll
        for (int c = 0; c < 4; ++c) {
          bf16x8 kf = ld256(kv, kt2 * 16 + q15, c * 64 + g * 16);
          st0 = mfma16(kf, qf[0][c], st0);
          st1 = mfma16(kf, qf[1][c], st1);
        }
#pragma unroll
        for (int r = 0; r < 4; ++r) {
          pf[0][kt2 * 4 + r] = st0[r];
          pf[1][kt2 * 4 + r] = st1[r];
        }
      }

      if (s < 2) {  // causal mask if this tile is diagonal for this wave
        const int qrb = 32 * w - 64 * s;
        if (qrb >= 0 && qrb < 64) {
#pragma unroll
          for (int qs = 0; qs < 2; ++qs) {
            const int qrel = qrb + 16 * qs + q15;
#pragma unroll
            for (int kt2 = 0; kt2 < 4; ++kt2)
#pragma unroll
              for (int r = 0; r < 4; ++r)
                if (kt2 * 16 + g * 4 + r > qrel) pf[qs][kt2 * 4 + r] = -1e30f;
          }
        }
      }
    }

    __builtin_amdgcn_s_barrier();            // C: all waves done reading kv(s)
    asm volatile("" ::: "memory");
    if (s + 2 < nt) STAGE(s & 1, TIDX(s + 2));   // D: refill this buffer

    if (!inactive) {
      // E: online softmax (defer-max)
      float tmax[2];
#pragma unroll
      for (int qs = 0; qs < 2; ++qs) {
        float m0 = fmaxf(fmaxf(pf[qs][0], pf[qs][1]), fmaxf(pf[qs][2], pf[qs][3]));
        float m1 = fmaxf(fmaxf(pf[qs][4], pf[qs][5]), fmaxf(pf[qs][6], pf[qs][7]));
        float m2 = fmaxf(fmaxf(pf[qs][8], pf[qs][9]), fmaxf(pf[qs][10], pf[qs][11]));
        float m3 = fmaxf(fmaxf(pf[qs][12], pf[qs][13]), fmaxf(pf[qs][14], pf[qs][15]));
        float tm = fmaxf(fmaxf(m0, m1), fmaxf(m2, m3));
        tm = fmaxf(tm, __shfl_xor(tm, 16));
        tm = fmaxf(tm, __shfl_xor(tm, 32));
        tmax[qs] = tm;
      }

      if (__all((tmax[0] <= mrun[0]) && (tmax[1] <= mrun[1]))) {
#pragma unroll
        for (int qs = 0; qs < 2; ++qs) {
          const float nmc = -mrun[qs] * SCALE_LOG2E;
#pragma unroll
          for (int i = 0; i < 16; ++i)
            pf[qs][i] = exp2f(fmaf(pf[qs][i], SCALE_LOG2E, nmc));
        }
      } else {
#pragma unroll
        for (int qs = 0; qs < 2; ++qs) {
          const float mnew = fmaxf(mrun[qs], tmax[qs]);
          const float al = exp2f((mrun[qs] - mnew) * SCALE_LOG2E);
          mrun[qs] = mnew;
          const float nmc = -mnew * SCALE_LOG2E;
#pragma unroll
          for (int i = 0; i < 16; ++i)
            pf[qs][i] = exp2f(fmaf(pf[qs][i], SCALE_LOG2E, nmc));
          lrun[qs] *= al;
          float ar[4];
#pragma unroll
          for (int r = 0; r < 4; ++r) ar[r] = __shfl(al, g * 4 + r);
#pragma unroll
          for (int dt = 0; dt < 8; ++dt)
#pragma unroll
            for (int r = 0; r < 4; ++r) acc[qs][dt][r] *= ar[r];
        }
      }

#pragma unroll
      for (int qs = 0; qs < 2; ++qs) {
        float s01 = (pf[qs][0] + pf[qs][1]) + (pf[qs][2] + pf[qs][3]);
        float s23 = (pf[qs][4] + pf[qs][5]) + (pf[qs][6] + pf[qs][7]);
        float s45 = (pf[qs][8] + pf[qs][9]) + (pf[qs][10] + pf[qs][11]);
        float s67 = (pf[qs][12] + pf[qs][13]) + (pf[qs][14] + pf[qs][15]);
        lrun[qs] += (s01 + s23) + (s45 + s67);
      }

      // P -> LDS (per-wave region, swizzled)
#pragma unroll
      for (int qs = 0; qs < 2; ++qs)
#pragma unroll
        for (int kt2 = 0; kt2 < 4; ++kt2) {
          u16x4 o = {f2bf(pf[qs][kt2 * 4]), f2bf(pf[qs][kt2 * 4 + 1]),
                     f2bf(pf[qs][kt2 * 4 + 2]), f2bf(pf[qs][kt2 * 4 + 3])};
          const int off =
              ((16 * qs + q15) * 128 + kt2 * 32 + g * 8) ^ ((q15 & 7) << 4);
          *(u16x4*)((char*)plw + off) = o;
        }
      asm volatile("s_waitcnt lgkmcnt(0)" ::: "memory");
    }

    // F: vb(s) registers ready (newest 4 outstanding = kv(s+2) stage, if any)
    if (s + 2 < nt) asm volatile("s_waitcnt vmcnt(4)" ::: "memory");
    else            asm volatile("s_waitcnt vmcnt(0)" ::: "memory");

    if (!inactive) {
      // G: PV: acc[qs][dt] += P(16x64) * V(64x16 slice dt), V from registers
      bf16x8 pa[2][2];
#pragma unroll
      for (int qs = 0; qs < 2; ++qs) {
        pa[qs][0] = ld128(plw, 16 * qs + q15, g * 16);
        pa[qs][1] = ld128(plw, 16 * qs + q15, 64 + g * 16);
      }
#pragma unroll
      for (int dt = 0; dt < 8; ++dt) {
#pragma unroll
        for (int qs = 0; qs < 2; ++qs) {
          acc[qs][dt] = mfma16(pa[qs][0], vbr[0][dt], acc[qs][dt]);
          acc[qs][dt] = mfma16(pa[qs][1], vbr[1][dt], acc[qs][dt]);
        }
      }
    }

    if (s + 1 < nt) VLOAD(s + 1);   // H: prefetch next V frags (regs now free)
  }

  // combine the 4 g-groups' partial row sums
#pragma unroll
  for (int qs = 0; qs < 2; ++qs) {
    lrun[qs] += __shfl_xor(lrun[qs], 16);
    lrun[qs] += __shfl_xor(lrun[qs], 32);
  }

  float* ob = out + ((size_t)b * TL + q0 + 32 * w) * TE + h * TD;
#pragma unroll
  for (int qs = 0; qs < 2; ++qs) {
    const float inv = 1.f / lrun[qs];
    float ir[4];
#pragma unroll
    for (int r = 0; r < 4; ++r) ir[r] = __shfl(inv, g * 4 + r);
#pragma unroll
    for (int dt = 0; dt < 8; ++dt)
#pragma unroll
      for (int r = 0; r < 4; ++r)
        ob[(16 * qs + g * 4 + r) * TE + dt * 16 + q15] = acc[qs][dt][r] * ir[r];
  }
}

// ---------------- fallback (v1-style, self-contained, no ws needed) ---------
__device__ __forceinline__ void stage_tile_fb(const float* __restrict__ src,
                                              unsigned short* kv, unsigned short* kvt,
                                              int t) {
  const int kr = (t >> 4) << 2;
  const int d0 = (t & 15) << 3;
  unsigned short c[4][8];
#pragma unroll
  for (int rr = 0; rr < 4; ++rr) {
    const float* p = src + (kr + rr) * TE + d0;
    const float4 a = *(const float4*)p;
    const float4 b = *(const float4*)(p + 4);
    c[rr][0] = f2bf(a.x); c[rr][1] = f2bf(a.y); c[rr][2] = f2bf(a.z); c[rr][3] = f2bf(a.w);
    c[rr][4] = f2bf(b.x); c[rr][5] = f2bf(b.y); c[rr][6] = f2bf(b.z); c[rr][7] = f2bf(b.w);
  }
#pragma unroll
  for (int rr = 0; rr < 4; ++rr) {
    const int r = kr + rr;
    u16x8 o = {c[rr][0], c[rr][1], c[rr][2], c[rr][3],
               c[rr][4], c[rr][5], c[rr][6], c[rr][7]};
    const int off = (r * 256 + d0 * 2) ^ ((r & 7) << 4);
    *(u16x8*)((char*)kv + off) = o;
  }
#pragma unroll
  for (int cc = 0; cc < 8; ++cc) {
    const int d = d0 + cc;
    u16x4 o = {c[0][cc], c[1][cc], c[2][cc], c[3][cc]};
    const int off = (d * 128 + kr * 2) ^ ((d & 7) << 4);
    *(u16x4*)((char*)kvt + off) = o;
  }
}

__global__ void __launch_bounds__(256)
evo_attn(const float* __restrict__ x, float* __restrict__ out) {
  __shared__ unsigned short kv[KB * TD];
  __shared__ unsigned short kvt[TD * KB];
  __shared__ unsigned short pl[4 * 16 * KB];

  const int t = threadIdx.x;
  const int lane = t & 63;
  const int w = t >> 6;
  const int g = lane >> 4;
  const int q15 = lane & 15;

  const int bh = blockIdx.x & 31;
  const int qt = 31 - (blockIdx.x >> 5);
  const int b = bh >> 4;
  const int h = bh & 15;
  const float* xb = x + (size_t)b * TL * TE + h * TD;
  const int q0 = qt * KB;

  stage_tile_fb(xb + (size_t)q0 * TE, kv, kvt, t);
  __syncthreads();

  bf16x8 qf[4];
#pragma unroll
  for (int c = 0; c < 4; ++c)
    qf[c] = ld256(kv, 16 * w + q15, c * 64 + g * 16);

  f32x4 acc[8];
#pragma unroll
  for (int dt = 0; dt < 8; ++dt) acc[dt] = (f32x4){0.f, 0.f, 0.f, 0.f};
  float mrun = -1e30f;
  float lrun = 0.f;
  unsigned short* plw = pl + w * (16 * KB);

  for (int s = 0; s <= qt; ++s) {
    if (s > 0) {
      __syncthreads();
      stage_tile_fb(xb + (size_t)(s - 1) * KB * TE, kv, kvt, t);
      __syncthreads();
    }
    float sv[16];
#pragma unroll
    for (int kt2 = 0; kt2 < 4; ++kt2) {
      f32x4 st = (f32x4){0.f, 0.f, 0.f, 0.f};
#pragma unroll
      for (int c = 0; c < 4; ++c) {
        bf16x8 kf = ld256(kv, kt2 * 16 + q15, c * 64 + g * 16);
        st = mfma16(kf, qf[c], st);
      }
#pragma unroll
      for (int r = 0; r < 4; ++r) sv[kt2 * 4 + r] = st[r] * SCALE_LOG2E;
    }
    if (s == 0) {
      const int qrel = 16 * w + q15;
#pragma unroll
      for (int kt2 = 0; kt2 < 4; ++kt2)
#pragma unroll
        for (int r = 0; r < 4; ++r)
          if (kt2 * 16 + g * 4 + r > qrel) sv[kt2 * 4 + r] = -1e30f;
    }
    float tmax = sv[0];
#pragma unroll
    for (int i = 1; i < 16; ++i) tmax = fmaxf(tmax, sv[i]);
    tmax = fmaxf(tmax, __shfl_xor(tmax, 16));
    tmax = fmaxf(tmax, __shfl_xor(tmax, 32));
    const float mnew = fmaxf(mrun, tmax);
    const float al = exp2f(mrun - mnew);
    mrun = mnew;
    float psum = 0.f;
    unsigned short pb[16];
#pragma unroll
    for (int i = 0; i < 16; ++i) {
      const float p = exp2f(sv[i] - mnew);
      psum += p;
      pb[i] = f2bf(p);
    }
    lrun = lrun * al + psum;
#pragma unroll
    for (int kt2 = 0; kt2 < 4; ++kt2) {
      u16x4 o = {pb[kt2 * 4], pb[kt2 * 4 + 1], pb[kt2 * 4 + 2], pb[kt2 * 4 + 3]};
      const int off = (q15 * 128 + kt2 * 32 + g * 8) ^ ((q15 & 7) << 4);
      *(u16x4*)((char*)plw + off) = o;
    }
    asm volatile("s_waitcnt lgkmcnt(0)" ::: "memory");
    float ar[4];
#pragma unroll
    for (int r = 0; r < 4; ++r) ar[r] = __shfl(al, g * 4 + r);
#pragma unroll
    for (int dt = 0; dt < 8; ++dt)
#pragma unroll
      for (int r = 0; r < 4; ++r) acc[dt][r] *= ar[r];
    bf16x8 pa0 = ld128(plw, q15, g * 16);
    bf16x8 pa1 = ld128(plw, q15, 64 + g * 16);
#pragma unroll
    for (int dt = 0; dt < 8; ++dt) {
      bf16x8 vb0 = ld128(kvt, dt * 16 + q15, g * 16);
      bf16x8 vb1 = ld128(kvt, dt * 16 + q15, 64 + g * 16);
      acc[dt] = mfma16(pa0, vb0, acc[dt]);
      acc[dt] = mfma16(pa1, vb1, acc[dt]);
    }
  }

  lrun += __shfl_xor(lrun, 16);
  lrun += __shfl_xor(lrun, 32);
  const float inv = 1.f / lrun;
  float ir[4];
#pragma unroll
  for (int r = 0; r < 4; ++r) ir[r] = __shfl(inv, g * 4 + r);
  float* ob = out + ((size_t)b * TL + q0 + 16 * w) * TE + h * TD;
#pragma unroll
  for (int dt = 0; dt < 8; ++dt)
#pragma unroll
    for (int r = 0; r < 4; ++r)
      ob[(g * 4 + r) * TE + dt * 16 + q15] = acc[dt][r] * ir[r];
}

extern "C" void kernel_launch(void* const* d_in, const int* in_sizes, int n_in,
                              void* d_out, int out_size, void* d_ws, size_t ws_size,
                              hipStream_t stream) {
  const float* x = (const float*)d_in[0];
  float* out = (float*)d_out;
  (void)in_sizes; (void)n_in; (void)out_size;
  if (ws_size >= (size_t)WS_NEED) {
    char* wsb = (char*)d_ws;
    prepack<<<dim3(1024), dim3(256), 0, stream>>>(x, wsb);
    evo_attn2<<<dim3(512), dim3(256), 0, stream>>>(wsb, out);
  } else {
    evo_attn<<<dim3(1024), dim3(256), 0, stream>>>(x, out);
  }
}

// Round 8
// 90.772 us; speedup vs baseline: 2.3311x; 1.5187x over previous
//
#include <hip/hip_runtime.h>
#include <hip/hip_bf16.h>

// EvoAttn: causal self-attention with Q=K=V = x.reshape(B,L,H,D).
// B=2 H=16 L=2048 D=128, fp32 in/out, bf16 MFMA compute.
// v8: perfect load balance — each block does q-tile pair (a, 31-a) = 33 steps.
//     512 blocks x 256 thr, 56KB LDS (2 blocks/CU), fragment-order V in LDS,
//     XCD-affine bh mapping.

#define TL 2048
#define TE 2048
#define TD 128
#define KB 64
#define NTILES 32                          // TL / KB
#define TILE_B 16384                       // 64*128*2 bytes
#define KV_REGION (32 * NTILES * TILE_B)   // 16 MB per layout
#define WS_NEED (2u * (unsigned)KV_REGION) // 32 MB

typedef __attribute__((ext_vector_type(8))) short bf16x8;
typedef __attribute__((ext_vector_type(4))) float f32x4;
typedef __attribute__((ext_vector_type(8))) unsigned short u16x8;
typedef __attribute__((ext_vector_type(4))) unsigned short u16x4;

// (1/sqrt(128)) * log2(e)
#define SCALE_LOG2E 0.12751879f

__device__ __forceinline__ unsigned short f2bf(float f) {
  __hip_bfloat16 h = __float2bfloat16(f);
  return __builtin_bit_cast(unsigned short, h);
}

__device__ __forceinline__ f32x4 mfma16(bf16x8 a, bf16x8 b, f32x4 c) {
  return __builtin_amdgcn_mfma_f32_16x16x32_bf16(a, b, c, 0, 0, 0);
}

__device__ __forceinline__ void gl_lds16(const void* g, void* l) {
  __builtin_amdgcn_global_load_lds(
      (__attribute__((address_space(1))) void*)(g),
      (__attribute__((address_space(3))) void*)(l), 16, 0, 0);
}

__device__ __forceinline__ bf16x8 ld256(const unsigned short* base, int row, int inrow) {
  const int off = (row * 256 + inrow) ^ ((row & 7) << 4);
  return *(const bf16x8*)((const char*)base + off);
}
__device__ __forceinline__ bf16x8 ld128(const unsigned short* base, int row, int inrow) {
  const int off = (row * 128 + inrow) ^ ((row & 7) << 4);
  return *(const bf16x8*)((const char*)base + off);
}

// kv region: per-tile LDS byte image [64 k][128 d] bf16, byte ^= (k&7)<<4.
// kvt region: per-tile FRAGMENT-ORDER V: 16B frag (half,dt,g,q15) at byte
//   ((half*8+dt)*64 + g*16 + q15)*16, holding V[k=half*32+g*8+j][d=dt*16+q15].
__global__ void __launch_bounds__(256)
prepack(const float* __restrict__ x, char* __restrict__ wsb) {
  const int bid = blockIdx.x;            // bh*32 + kt
  const int kt = bid & 31;
  const int bh = bid >> 5;
  const int b = bh >> 4;
  const int h = bh & 15;
  const float* src = x + (size_t)b * TL * TE + h * TD + (size_t)kt * KB * TE;
  const int t = threadIdx.x;
  const int kr = (t >> 4) << 2;          // 4 consecutive k-rows
  const int d0 = (t & 15) << 3;          // 8 d-cols
  unsigned short c[4][8];
#pragma unroll
  for (int rr = 0; rr < 4; ++rr) {
    const float* p = src + (kr + rr) * TE + d0;
    const float4 a = *(const float4*)p;
    const float4 bb = *(const float4*)(p + 4);
    c[rr][0] = f2bf(a.x);  c[rr][1] = f2bf(a.y);  c[rr][2] = f2bf(a.z);  c[rr][3] = f2bf(a.w);
    c[rr][4] = f2bf(bb.x); c[rr][5] = f2bf(bb.y); c[rr][6] = f2bf(bb.z); c[rr][7] = f2bf(bb.w);
  }
  // K-layout tile (LDS image, swizzled)
  char* gkv = wsb + (size_t)bid * TILE_B;
#pragma unroll
  for (int rr = 0; rr < 4; ++rr) {
    const int r = kr + rr;
    u16x8 o = {c[rr][0], c[rr][1], c[rr][2], c[rr][3],
               c[rr][4], c[rr][5], c[rr][6], c[rr][7]};
    const int off = (r * 256 + d0 * 2) ^ ((r & 7) << 4);
    *(u16x8*)(gkv + off) = o;
  }
  // V-layout tile (fragment order)
  char* gkt = wsb + KV_REGION + (size_t)bid * TILE_B;
  const int half = kr >> 5;
  const int g = (kr >> 3) & 3;
  const int j0 = kr & 7;                 // 0 or 4
#pragma unroll
  for (int cc = 0; cc < 8; ++cc) {
    const int d = d0 + cc;
    u16x4 o = {c[0][cc], c[1][cc], c[2][cc], c[3][cc]};   // k = kr..kr+3
    const int off = (((half * 8 + (d >> 4)) * 64 + g * 16 + (d & 15)) << 4) + j0 * 2;
    *(u16x4*)(gkt + off) = o;
  }
}

// ---------------- main attention kernel: pair (a, 31-a), 33 steps/block -----
__global__ void __launch_bounds__(256)
evo_attn2(const char* __restrict__ wsb, float* __restrict__ out) {
  // kv0 | kv1 | kvt | pl(4 waves x 2KB) = 56 KB -> 2 blocks/CU
  __shared__ char smem[3 * TILE_B + 8192];

  const int t = threadIdx.x;
  const int lane = t & 63;
  const int w = t >> 6;        // wave 0..3, owns q rows [q0+16w, q0+16w+16)
  const int g = lane >> 4;
  const int q15 = lane & 15;

  const int blk = blockIdx.x;            // 512 blocks
  // XCD-affine: xcd = blk&7 serves bh in {4*xcd .. 4*xcd+3}
  const int bh = (blk & 7) * 4 + (blk >> 7);
  const int a = (blk >> 3) & 15;         // pair index: q-tiles a and 31-a
  const int b = bh >> 4;
  const int h = bh & 15;

  const char* gkv = wsb + (size_t)bh * (NTILES * TILE_B);
  const char* gkt = wsb + KV_REGION + (size_t)bh * (NTILES * TILE_B);
  unsigned short* plw = (unsigned short*)(smem + 3 * TILE_B) + w * (16 * KB);
  const char* kvtb = smem + 2 * TILE_B;

  // 256 threads stage one 16KB tile: 4 gl_lds16/thread; LDS dest is
  // wave-uniform base + lane*16 -> per-wave 1KB chunks at (t>>6)*1024.
#define STAGE_KV(BUFI, KT)                                                 \
  {                                                                        \
    char* dst_ = smem + (BUFI) * TILE_B + (t >> 6) * 1024;                 \
    const char* src_ = gkv + (size_t)(KT) * TILE_B + t * 16;               \
    _Pragma("unroll")                                                      \
    for (int i_ = 0; i_ < 4; ++i_) gl_lds16(src_ + i_ * 4096, dst_ + i_ * 4096); \
  }
#define STAGE_KVT(KT)                                                      \
  {                                                                        \
    char* dst_ = smem + 2 * TILE_B + (t >> 6) * 1024;                      \
    const char* src_ = gkt + (size_t)(KT) * TILE_B + t * 16;               \
    _Pragma("unroll")                                                      \
    for (int i_ = 0; i_ < 4; ++i_) gl_lds16(src_ + i_ * 4096, dst_ + i_ * 4096); \
  }

#pragma unroll 1
  for (int seg = 0; seg < 2; ++seg) {
    const int qt = seg ? (31 - a) : a;   // q-tile index, rows [64qt, 64qt+64)
    const int nt = qt + 1;               // tiles: s=0 diag(qt), s>0 -> s-1

    // prologue: diag kv + kv tile 0 + diag kvt
    STAGE_KV(0, qt);
    if (nt > 1) STAGE_KV(1, 0);
    STAGE_KVT(qt);
    asm volatile("s_waitcnt vmcnt(0)" ::: "memory");
    __builtin_amdgcn_s_barrier();
    asm volatile("" ::: "memory");

    // Q fragments from buf0 (the diagonal tile IS the Q tile)
    bf16x8 qf[4];
#pragma unroll
    for (int c = 0; c < 4; ++c)
      qf[c] = ld256((const unsigned short*)smem, 16 * w + q15, c * 64 + g * 16);

    f32x4 acc[8];
#pragma unroll
    for (int dt = 0; dt < 8; ++dt) acc[dt] = (f32x4){0.f, 0.f, 0.f, 0.f};
    float mrun = -1e30f;   // raw score domain
    float lrun = 0.f;

    for (int s = 0; s < nt; ++s) {
      if (s > 0) {  // kv(s) ready; queue <= [kvt(s):4, kv(s+1):4]
        asm volatile("s_waitcnt vmcnt(8)" ::: "memory");
        __builtin_amdgcn_s_barrier();
        asm volatile("" ::: "memory");
      }
      const unsigned short* kv = (const unsigned short*)(smem + (s & 1) * TILE_B);

      // QK^T: lane (g,q15) holds S[k=kt2*16+g*4+r][q=16w+q15] (raw)
      float sv[16];
      __builtin_amdgcn_s_setprio(1);
#pragma unroll
      for (int kt2 = 0; kt2 < 4; ++kt2) {
        f32x4 st = (f32x4){0.f, 0.f, 0.f, 0.f};
#pragma unroll
        for (int c = 0; c < 4; ++c) {
          bf16x8 kf = ld256(kv, kt2 * 16 + q15, c * 64 + g * 16);
          st = mfma16(kf, qf[c], st);
        }
#pragma unroll
        for (int r = 0; r < 4; ++r) sv[kt2 * 4 + r] = st[r];
      }
      __builtin_amdgcn_s_setprio(0);

      if (s == 0) {  // diagonal causal mask
        const int qrel = 16 * w + q15;
#pragma unroll
        for (int kt2 = 0; kt2 < 4; ++kt2)
#pragma unroll
          for (int r = 0; r < 4; ++r)
            if (kt2 * 16 + g * 4 + r > qrel) sv[kt2 * 4 + r] = -1e30f;
      }

      // online softmax, defer-max fast path
      float m0 = fmaxf(fmaxf(sv[0], sv[1]), fmaxf(sv[2], sv[3]));
      float m1 = fmaxf(fmaxf(sv[4], sv[5]), fmaxf(sv[6], sv[7]));
      float m2 = fmaxf(fmaxf(sv[8], sv[9]), fmaxf(sv[10], sv[11]));
      float m3 = fmaxf(fmaxf(sv[12], sv[13]), fmaxf(sv[14], sv[15]));
      float tmax = fmaxf(fmaxf(m0, m1), fmaxf(m2, m3));
      tmax = fmaxf(tmax, __shfl_xor(tmax, 16));
      tmax = fmaxf(tmax, __shfl_xor(tmax, 32));

      float pf[16];
      if (__all(tmax <= mrun)) {
        const float nmc = -mrun * SCALE_LOG2E;
#pragma unroll
        for (int i = 0; i < 16; ++i) pf[i] = exp2f(fmaf(sv[i], SCALE_LOG2E, nmc));
      } else {
        const float mnew = fmaxf(mrun, tmax);
        const float al = exp2f((mrun - mnew) * SCALE_LOG2E);
        mrun = mnew;
        const float nmc = -mnew * SCALE_LOG2E;
#pragma unroll
        for (int i = 0; i < 16; ++i) pf[i] = exp2f(fmaf(sv[i], SCALE_LOG2E, nmc));
        lrun *= al;
        float ar[4];
#pragma unroll
        for (int r = 0; r < 4; ++r) ar[r] = __shfl(al, g * 4 + r);
#pragma unroll
        for (int dt = 0; dt < 8; ++dt)
#pragma unroll
          for (int r = 0; r < 4; ++r) acc[dt][r] *= ar[r];
      }
      {
        float s01 = (pf[0] + pf[1]) + (pf[2] + pf[3]);
        float s23 = (pf[4] + pf[5]) + (pf[6] + pf[7]);
        float s45 = (pf[8] + pf[9]) + (pf[10] + pf[11]);
        float s67 = (pf[12] + pf[13]) + (pf[14] + pf[15]);
        lrun += (s01 + s23) + (s45 + s67);
      }

      // P -> per-wave LDS (swizzled), then own-wave readback
#pragma unroll
      for (int kt2 = 0; kt2 < 4; ++kt2) {
        u16x4 o = {f2bf(pf[kt2 * 4]), f2bf(pf[kt2 * 4 + 1]),
                   f2bf(pf[kt2 * 4 + 2]), f2bf(pf[kt2 * 4 + 3])};
        const int off = (q15 * 128 + kt2 * 32 + g * 8) ^ ((q15 & 7) << 4);
        *(u16x4*)((char*)plw + off) = o;
      }
      asm volatile("s_waitcnt lgkmcnt(0)" ::: "memory");

      if (s > 0) {  // kvt(s) ready; leave kv(s+1):4 outstanding if staged
        if (s + 1 < nt) asm volatile("s_waitcnt vmcnt(4)" ::: "memory");
        else            asm volatile("s_waitcnt vmcnt(0)" ::: "memory");
        __builtin_amdgcn_s_barrier();
        asm volatile("" ::: "memory");
      }

      // PV: acc[dt] += P(16x64) * V(64x16 slice dt); V frags linear in LDS
      bf16x8 pa0 = ld128(plw, q15, g * 16);
      bf16x8 pa1 = ld128(plw, q15, 64 + g * 16);
      __builtin_amdgcn_s_setprio(1);
#pragma unroll
      for (int dt = 0; dt < 8; ++dt) {
        bf16x8 vb0 = *(const bf16x8*)(kvtb + dt * 1024 + lane * 16);
        bf16x8 vb1 = *(const bf16x8*)(kvtb + (8 + dt) * 1024 + lane * 16);
        acc[dt] = mfma16(pa0, vb0, acc[dt]);
        acc[dt] = mfma16(pa1, vb1, acc[dt]);
      }
      __builtin_amdgcn_s_setprio(0);

      // all waves done reading kv(s)/kvt(s); refill
      __builtin_amdgcn_s_barrier();
      asm volatile("" ::: "memory");
      if (s + 1 < nt) STAGE_KVT(s);          // tile(s+1) = s
      if (s + 2 < nt) STAGE_KV(s & 1, s + 1);// tile(s+2) = s+1, buf (s+2)&1
    }

    // combine g-group partial sums, normalize, write out
    lrun += __shfl_xor(lrun, 16);
    lrun += __shfl_xor(lrun, 32);
    const float inv = 1.f / lrun;
    float ir[4];
#pragma unroll
    for (int r = 0; r < 4; ++r) ir[r] = __shfl(inv, g * 4 + r);

    float* ob = out + ((size_t)b * TL + qt * 64 + 16 * w) * TE + h * TD;
#pragma unroll
    for (int dt = 0; dt < 8; ++dt)
#pragma unroll
      for (int r = 0; r < 4; ++r)
        ob[(g * 4 + r) * TE + dt * 16 + q15] = acc[dt][r] * ir[r];

    __builtin_amdgcn_s_barrier();  // don't let seg-2 prologue race seg-1 reads
    asm volatile("" ::: "memory");
  }
}

// ---------------- fallback (v1-style, self-contained, no ws needed) ---------
__device__ __forceinline__ void stage_tile_fb(const float* __restrict__ src,
                                              unsigned short* kv, unsigned short* kvt,
                                              int t) {
  const int kr = (t >> 4) << 2;
  const int d0 = (t & 15) << 3;
  unsigned short c[4][8];
#pragma unroll
  for (int rr = 0; rr < 4; ++rr) {
    const float* p = src + (kr + rr) * TE + d0;
    const float4 a = *(const float4*)p;
    const float4 b = *(const float4*)(p + 4);
    c[rr][0] = f2bf(a.x); c[rr][1] = f2bf(a.y); c[rr][2] = f2bf(a.z); c[rr][3] = f2bf(a.w);
    c[rr][4] = f2bf(b.x); c[rr][5] = f2bf(b.y); c[rr][6] = f2bf(b.z); c[rr][7] = f2bf(b.w);
  }
#pragma unroll
  for (int rr = 0; rr < 4; ++rr) {
    const int r = kr + rr;
    u16x8 o = {c[rr][0], c[rr][1], c[rr][2], c[rr][3],
               c[rr][4], c[rr][5], c[rr][6], c[rr][7]};
    const int off = (r * 256 + d0 * 2) ^ ((r & 7) << 4);
    *(u16x8*)((char*)kv + off) = o;
  }
#pragma unroll
  for (int cc = 0; cc < 8; ++cc) {
    const int d = d0 + cc;
    u16x4 o = {c[0][cc], c[1][cc], c[2][cc], c[3][cc]};
    const int off = (d * 128 + kr * 2) ^ ((d & 7) << 4);
    *(u16x4*)((char*)kvt + off) = o;
  }
}

__global__ void __launch_bounds__(256)
evo_attn(const float* __restrict__ x, float* __restrict__ out) {
  __shared__ unsigned short kv[KB * TD];
  __shared__ unsigned short kvt[TD * KB];
  __shared__ unsigned short pl[4 * 16 * KB];

  const int t = threadIdx.x;
  const int lane = t & 63;
  const int w = t >> 6;
  const int g = lane >> 4;
  const int q15 = lane & 15;

  const int bh = blockIdx.x & 31;
  const int qt = 31 - (blockIdx.x >> 5);
  const int b = bh >> 4;
  const int h = bh & 15;
  const float* xb = x + (size_t)b * TL * TE + h * TD;
  const int q0 = qt * KB;

  stage_tile_fb(xb + (size_t)q0 * TE, kv, kvt, t);
  __syncthreads();

  bf16x8 qf[4];
#pragma unroll
  for (int c = 0; c < 4; ++c)
    qf[c] = ld256(kv, 16 * w + q15, c * 64 + g * 16);

  f32x4 acc[8];
#pragma unroll
  for (int dt = 0; dt < 8; ++dt) acc[dt] = (f32x4){0.f, 0.f, 0.f, 0.f};
  float mrun = -1e30f;
  float lrun = 0.f;
  unsigned short* plw = pl + w * (16 * KB);

  for (int s = 0; s <= qt; ++s) {
    if (s > 0) {
      __syncthreads();
      stage_tile_fb(xb + (size_t)(s - 1) * KB * TE, kv, kvt, t);
      __syncthreads();
    }
    float sv[16];
#pragma unroll
    for (int kt2 = 0; kt2 < 4; ++kt2) {
      f32x4 st = (f32x4){0.f, 0.f, 0.f, 0.f};
#pragma unroll
      for (int c = 0; c < 4; ++c) {
        bf16x8 kf = ld256(kv, kt2 * 16 + q15, c * 64 + g * 16);
        st = mfma16(kf, qf[c], st);
      }
#pragma unroll
      for (int r = 0; r < 4; ++r) sv[kt2 * 4 + r] = st[r] * SCALE_LOG2E;
    }
    if (s == 0) {
      const int qrel = 16 * w + q15;
#pragma unroll
      for (int kt2 = 0; kt2 < 4; ++kt2)
#pragma unroll
        for (int r = 0; r < 4; ++r)
          if (kt2 * 16 + g * 4 + r > qrel) sv[kt2 * 4 + r] = -1e30f;
    }
    float tmax = sv[0];
#pragma unroll
    for (int i = 1; i < 16; ++i) tmax = fmaxf(tmax, sv[i]);
    tmax = fmaxf(tmax, __shfl_xor(tmax, 16));
    tmax = fmaxf(tmax, __shfl_xor(tmax, 32));
    const float mnew = fmaxf(mrun, tmax);
    const float al = exp2f(mrun - mnew);
    mrun = mnew;
    float psum = 0.f;
    unsigned short pb[16];
#pragma unroll
    for (int i = 0; i < 16; ++i) {
      const float p = exp2f(sv[i] - mnew);
      psum += p;
      pb[i] = f2bf(p);
    }
    lrun = lrun * al + psum;
#pragma unroll
    for (int kt2 = 0; kt2 < 4; ++kt2) {
      u16x4 o = {pb[kt2 * 4], pb[kt2 * 4 + 1], pb[kt2 * 4 + 2], pb[kt2 * 4 + 3]};
      const int off = (q15 * 128 + kt2 * 32 + g * 8) ^ ((q15 & 7) << 4);
      *(u16x4*)((char*)plw + off) = o;
    }
    asm volatile("s_waitcnt lgkmcnt(0)" ::: "memory");
    float ar[4];
#pragma unroll
    for (int r = 0; r < 4; ++r) ar[r] = __shfl(al, g * 4 + r);
#pragma unroll
    for (int dt = 0; dt < 8; ++dt)
#pragma unroll
      for (int r = 0; r < 4; ++r) acc[dt][r] *= ar[r];
    bf16x8 pa0 = ld128(plw, q15, g * 16);
    bf16x8 pa1 = ld128(plw, q15, 64 + g * 16);
#pragma unroll
    for (int dt = 0; dt < 8; ++dt) {
      bf16x8 vb0 = ld128(kvt, dt * 16 + q15, g * 16);
      bf16x8 vb1 = ld128(kvt, dt * 16 + q15, 64 + g * 16);
      acc[dt] = mfma16(pa0, vb0, acc[dt]);
      acc[dt] = mfma16(pa1, vb1, acc[dt]);
    }
  }

  lrun += __shfl_xor(lrun, 16);
  lrun += __shfl_xor(lrun, 32);
  const float inv = 1.f / lrun;
  float ir[4];
#pragma unroll
  for (int r = 0; r < 4; ++r) ir[r] = __shfl(inv, g * 4 + r);
  float* ob = out + ((size_t)b * TL + q0 + 16 * w) * TE + h * TD;
#pragma unroll
  for (int dt = 0; dt < 8; ++dt)
#pragma unroll
    for (int r = 0; r < 4; ++r)
      ob[(g * 4 + r) * TE + dt * 16 + q15] = acc[dt][r] * ir[r];
}

extern "C" void kernel_launch(void* const* d_in, const int* in_sizes, int n_in,
                              void* d_out, int out_size, void* d_ws, size_t ws_size,
                              hipStream_t stream) {
  const float* x = (const float*)d_in[0];
  float* out = (float*)d_out;
  (void)in_sizes; (void)n_in; (void)out_size;
  if (ws_size >= (size_t)WS_NEED) {
    char* wsb = (char*)d_ws;
    prepack<<<dim3(1024), dim3(256), 0, stream>>>(x, wsb);
    evo_attn2<<<dim3(512), dim3(256), 0, stream>>>(wsb, out);
  } else {
    evo_attn<<<dim3(1024), dim3(256), 0, stream>>>(x, out);
  }
}